// Round 1
// baseline (553.552 us; speedup 1.0000x reference)
//
#include <hip/hip_runtime.h>

// ---------- types ----------
typedef float    f32x4 __attribute__((ext_vector_type(4)));
typedef short    bf16x8 __attribute__((ext_vector_type(8)));
typedef unsigned short u16;
typedef u16      u16x4 __attribute__((ext_vector_type(4)));

#define MFMA16(a, b, c) __builtin_amdgcn_mfma_f32_16x16x32_bf16((a), (b), (c), 0, 0, 0)

#define CCH 512          // channels
#define NPIX 4096        // 64*64 pixels
#define NHEAD 4
#define HC 128           // head channels
#define QK_SCALE 0.04419417382415922f   // 1/sqrt(512)  (repo quirk: full C)

__device__ __forceinline__ u16 f2b(float f) {
  unsigned u = __builtin_bit_cast(unsigned, f);
  u += 0x7FFFu + ((u >> 16) & 1u);      // RNE
  return (u16)(u >> 16);
}

__device__ __forceinline__ void gl_lds16(const u16* g, u16* l) {
  __builtin_amdgcn_global_load_lds((const __attribute__((address_space(1))) void*)g,
                                   (__attribute__((address_space(3))) void*)l, 16, 0, 0);
}

__device__ __forceinline__ f32x4 max4(f32x4 a, f32x4 b) {
  f32x4 r;
  #pragma unroll
  for (int i = 0; i < 4; ++i) r[i] = fmaxf(a[i], b[i]);
  return r;
}

// ---------- 1. weights fp32 -> bf16 ----------
__global__ void wconv_k(const float* __restrict__ w0, const float* __restrict__ w1,
                        const float* __restrict__ w2, const float* __restrict__ w3,
                        u16* __restrict__ dst) {
  int m = blockIdx.y;
  const float* src = (m == 0) ? w0 : (m == 1) ? w1 : (m == 2) ? w2 : w3;
  int i = (blockIdx.x * 256 + threadIdx.x) * 4;
  f32x4 v = *(const f32x4*)(src + i);
  u16x4 o = { f2b(v[0]), f2b(v[1]), f2b(v[2]), f2b(v[3]) };
  *(u16x4*)(dst + (size_t)m * (CCH * CCH) + i) = o;
}

// ---------- 2. GroupNorm statistics: one block per (b, group) ----------
__global__ void gn_stats_k(const float* __restrict__ x, float* __restrict__ stats) {
  int bg = blockIdx.x;                       // 0..63 ; contiguous 16ch*4096 slab
  const f32x4* p = (const f32x4*)(x + (size_t)bg * 65536);
  int t = threadIdx.x, wv = t >> 6, l = t & 63;
  float s = 0.f, ss = 0.f;
  for (int i = t; i < 16384; i += 256) {
    f32x4 v = p[i];
    s  += v[0] + v[1] + v[2] + v[3];
    ss += v[0]*v[0] + v[1]*v[1] + v[2]*v[2] + v[3]*v[3];
  }
  #pragma unroll
  for (int d = 32; d; d >>= 1) { s += __shfl_down(s, d, 64); ss += __shfl_down(ss, d, 64); }
  __shared__ float red[8];
  if (l == 0) { red[wv*2] = s; red[wv*2+1] = ss; }
  __syncthreads();
  if (t == 0) {
    s  = red[0] + red[2] + red[4] + red[6];
    ss = red[1] + red[3] + red[5] + red[7];
    float mean = s * (1.f/65536.f);
    float var  = ss * (1.f/65536.f) - mean*mean;
    stats[bg*2]   = mean;
    stats[bg*2+1] = rsqrtf(var + 1e-6f);
  }
}

// ---------- 3. GN apply + transpose: x[b][c][n] -> Ht[b][n][c] bf16 ----------
// block covers 64c x 64n; thread owns a 4c x 4n register micro-tile.
__global__ void gn_norm_k(const float* __restrict__ x, const float* __restrict__ gns,
                          const float* __restrict__ gnb, const float* __restrict__ stats,
                          u16* __restrict__ Ht) {
  int t = threadIdx.x;
  int ct = blockIdx.x * 64, nt = blockIdx.y * 64, b = blockIdx.z;
  int c0 = ct + (t & 15) * 4;
  int n0 = nt + (t >> 4) * 4;
  const float* xb = x + ((size_t)b * CCH + c0) * NPIX + n0;
  int sidx = (b * 32 + (c0 >> 4)) * 2;
  float mean = stats[sidx], rstd = stats[sidx + 1];
  f32x4 rows[4];
  #pragma unroll
  for (int j = 0; j < 4; ++j) {
    f32x4 v = *(const f32x4*)(xb + (size_t)j * NPIX);
    float a  = rstd * gns[c0 + j];
    float bb = gnb[c0 + j] - mean * a;
    rows[j] = v * a + bb;
  }
  #pragma unroll
  for (int i = 0; i < 4; ++i) {
    u16x4 o = { f2b(rows[0][i]), f2b(rows[1][i]), f2b(rows[2][i]), f2b(rows[3][i]) };
    *(u16x4*)(Ht + ((size_t)b * NPIX + n0 + i) * CCH + c0) = o;
  }
}

// ---------- 4. NT GEMM: C[m][n] = sum_k A[m][k]*B[n][k] (+bias/resid) ----------
// MODE 0: A=Ht flat [8192][512], B=W [512][512]  -> outb[row=pix][col=o], bias[col]
// MODE 1: A=W, B=Ht[z]                           -> outb[z][row=o][col=pix], bias[row]
// MODE 2: A=Wo, B=Ot[z], resid=x                 -> outf[z][row=o][col=pix] fp32
template<int MODE>
__global__ __launch_bounds__(256) void gemm_nt(const u16* __restrict__ A,
                                               const u16* __restrict__ B,
                                               const float* __restrict__ bias,
                                               u16* __restrict__ outb,
                                               float* __restrict__ outf,
                                               const float* __restrict__ resid) {
  __shared__ __align__(16) u16 As[128 * 32];
  __shared__ __align__(16) u16 Bs[128 * 32];
  const int t = threadIdx.x, l = t & 63, wv = t >> 6;
  const int l16 = l & 15, lq = l >> 4;
  const int mt = blockIdx.x * 128, nt = blockIdx.y * 128, z = blockIdx.z;
  const u16* Ap = A + (size_t)mt * CCH;
  const u16* Bp = (MODE == 0) ? (B + (size_t)nt * CCH)
                              : (B + ((size_t)z * NPIX + nt) * CCH);
  const int wm = (wv >> 1) * 64, wn = (wv & 1) * 64;
  f32x4 acc[4][4] = {};
  for (int k0 = 0; k0 < CCH; k0 += 32) {
    __syncthreads();                 // prior reads done before restage
    #pragma unroll
    for (int j = 0; j < 2; ++j) {
      int idx = t + j * 256;         // 0..511 -> row=idx/4, 8-elem chunk idx%4
      int row = idx >> 2, kc = (idx & 3) * 8;
      gl_lds16(Ap + (size_t)row * CCH + k0 + kc, As + idx * 8);
      gl_lds16(Bp + (size_t)row * CCH + k0 + kc, Bs + idx * 8);
    }
    __syncthreads();                 // implicit vmcnt(0) drain
    bf16x8 af[4], bfr[4];
    #pragma unroll
    for (int i = 0; i < 4; ++i) {
      af[i]  = *(const bf16x8*)(As + (wm + i * 16 + l16) * 32 + lq * 8);
      bfr[i] = *(const bf16x8*)(Bs + (wn + i * 16 + l16) * 32 + lq * 8);
    }
    #pragma unroll
    for (int mi = 0; mi < 4; ++mi)
      #pragma unroll
      for (int ni = 0; ni < 4; ++ni)
        acc[mi][ni] = MFMA16(af[mi], bfr[ni], acc[mi][ni]);
  }
  #pragma unroll
  for (int mi = 0; mi < 4; ++mi)
    #pragma unroll
    for (int ni = 0; ni < 4; ++ni)
      #pragma unroll
      for (int r = 0; r < 4; ++r) {
        int grow = mt + wm + mi * 16 + lq * 4 + r;
        int gcol = nt + wn + ni * 16 + l16;
        float v = acc[mi][ni][r];
        if (MODE == 0) {
          outb[(size_t)grow * CCH + gcol] = f2b(v + bias[gcol]);
        } else if (MODE == 1) {
          outb[((size_t)z * CCH + grow) * NPIX + gcol] = f2b(v + bias[grow]);
        } else {
          size_t off = ((size_t)z * CCH + grow) * NPIX + gcol;
          outf[off] = v + bias[grow] + resid[off];
        }
      }
}

// ---------- 5. Flash attention ----------
// Qt,Kt: [b][n][512] bf16 (head = col slice). Vc: [b][512][n] bf16. Ot: [b][n][512].
// Block = 4 waves x 32 q-rows = 128 rows. K/V fragments read straight from L2
// (1 MB/head, cache-resident; no barriers in the loop). P transposed via
// per-wave XOR-swizzled LDS.
__global__ __launch_bounds__(256, 2) void flash_k(const u16* __restrict__ Qt,
                                                  const u16* __restrict__ Kt,
                                                  const u16* __restrict__ Vc,
                                                  u16* __restrict__ Ot) {
  __shared__ __align__(16) u16 P_lds[4 * 2048];   // per-wave [32][64]
  const int t = threadIdx.x, wv = t >> 6, l = t & 63;
  const int l16 = l & 15, lq = l >> 4;
  const int qt0 = blockIdx.x * 128 + wv * 32;
  const int hd = blockIdx.y, b = blockIdx.z;
  const u16* Q = Qt + ((size_t)b * NPIX + qt0) * CCH + hd * HC;
  const u16* K = Kt + (size_t)b * NPIX * CCH + hd * HC;
  const u16* V = Vc + (size_t)b * CCH * NPIX + (size_t)hd * HC * NPIX;
  u16* O = Ot + ((size_t)b * NPIX + qt0) * CCH + hd * HC;
  u16* P = &P_lds[wv * 2048];

  bf16x8 qf[2][4];
  #pragma unroll
  for (int mi = 0; mi < 2; ++mi)
    #pragma unroll
    for (int kk = 0; kk < 4; ++kk)
      qf[mi][kk] = *(const bf16x8*)(Q + (size_t)(mi * 16 + l16) * CCH + kk * 32 + lq * 8);

  f32x4 oacc[2][8] = {};
  f32x4 mrv[2], lrv[2];
  mrv[0] = -1e30f; mrv[1] = -1e30f; lrv[0] = 0.f; lrv[1] = 0.f;

  for (int m0 = 0; m0 < NPIX; m0 += 64) {
    // ---- S = (Q K^T) over this 64-key tile ----
    f32x4 S[2][4] = {};
    #pragma unroll
    for (int kk = 0; kk < 4; ++kk)
      #pragma unroll
      for (int mm = 0; mm < 4; ++mm) {
        bf16x8 kf = *(const bf16x8*)(K + (size_t)(m0 + mm * 16 + l16) * CCH + kk * 32 + lq * 8);
        S[0][mm] = MFMA16(qf[0][kk], kf, S[0][mm]);
        S[1][mm] = MFMA16(qf[1][kk], kf, S[1][mm]);
      }
    // ---- online softmax (rows live in vector-lane r; 16-lane butterfly) ----
    #pragma unroll
    for (int mi = 0; mi < 2; ++mi) {
      #pragma unroll
      for (int mm = 0; mm < 4; ++mm) S[mi][mm] = S[mi][mm] * QK_SCALE;
      f32x4 rm = max4(max4(S[mi][0], S[mi][1]), max4(S[mi][2], S[mi][3]));
      #pragma unroll
      for (int r = 0; r < 4; ++r) {
        float v = rm[r];
        #pragma unroll
        for (int d = 1; d < 16; d <<= 1) v = fmaxf(v, __shfl_xor(v, d, 64));
        rm[r] = v;
      }
      f32x4 mn = max4(mrv[mi], rm);
      f32x4 al, rs = 0.f;
      #pragma unroll
      for (int r = 0; r < 4; ++r) al[r] = __expf(mrv[mi][r] - mn[r]);
      #pragma unroll
      for (int mm = 0; mm < 4; ++mm) {
        f32x4 p;
        #pragma unroll
        for (int r = 0; r < 4; ++r) p[r] = __expf(S[mi][mm][r] - mn[r]);
        S[mi][mm] = p;
        rs += p;
      }
      #pragma unroll
      for (int r = 0; r < 4; ++r) {
        float v = rs[r];
        #pragma unroll
        for (int d = 1; d < 16; d <<= 1) v += __shfl_xor(v, d, 64);
        rs[r] = v;
      }
      lrv[mi] = lrv[mi] * al + rs;
      mrv[mi] = mn;
      #pragma unroll
      for (int cc = 0; cc < 8; ++cc) oacc[mi][cc] *= al;
      // P -> swizzled LDS (bf16)
      #pragma unroll
      for (int mm = 0; mm < 4; ++mm)
        #pragma unroll
        for (int r = 0; r < 4; ++r) {
          int row = mi * 16 + lq * 4 + r;
          int byte = row * 128 + (((mm * 16 + l16) * 2) ^ ((row & 7) << 4));
          *(u16*)((char*)P + byte) = f2b(S[mi][mm][r]);
        }
    }
    // ---- PV ----
    bf16x8 pa[2][2];
    #pragma unroll
    for (int mi = 0; mi < 2; ++mi)
      #pragma unroll
      for (int ks = 0; ks < 2; ++ks) {
        int row = mi * 16 + l16;
        int byte = row * 128 + ((ks * 64 + lq * 16) ^ ((row & 7) << 4));
        pa[mi][ks] = *(const bf16x8*)((char*)P + byte);
      }
    #pragma unroll
    for (int ks = 0; ks < 2; ++ks)
      #pragma unroll
      for (int cc = 0; cc < 8; ++cc) {
        bf16x8 vf = *(const bf16x8*)(V + (size_t)(cc * 16 + l16) * NPIX + m0 + ks * 32 + lq * 8);
        oacc[0][cc] = MFMA16(pa[0][ks], vf, oacc[0][cc]);
        oacc[1][cc] = MFMA16(pa[1][ks], vf, oacc[1][cc]);
      }
  }
  // ---- epilogue: divide by softmax denom, store bf16 ----
  #pragma unroll
  for (int mi = 0; mi < 2; ++mi) {
    f32x4 inv;
    #pragma unroll
    for (int r = 0; r < 4; ++r) inv[r] = 1.f / lrv[mi][r];
    #pragma unroll
    for (int cc = 0; cc < 8; ++cc)
      #pragma unroll
      for (int r = 0; r < 4; ++r)
        O[(size_t)(mi * 16 + lq * 4 + r) * CCH + cc * 16 + l16] = f2b(oacc[mi][cc][r] * inv[r]);
  }
}

// ---------- launch ----------
extern "C" void kernel_launch(void* const* d_in, const int* in_sizes, int n_in,
                              void* d_out, int out_size, void* d_ws, size_t ws_size,
                              hipStream_t stream) {
  const float* x   = (const float*)d_in[0];
  const float* gns = (const float*)d_in[1];
  const float* gnb = (const float*)d_in[2];
  const float* wq  = (const float*)d_in[3];
  const float* bq  = (const float*)d_in[4];
  const float* wk  = (const float*)d_in[5];
  const float* bk  = (const float*)d_in[6];
  const float* wv  = (const float*)d_in[7];
  const float* bv  = (const float*)d_in[8];
  const float* wo  = (const float*)d_in[9];
  const float* bo  = (const float*)d_in[10];
  float* out = (float*)d_out;
  char* ws = (char*)d_ws;

  u16*   wb    = (u16*)ws;                          // 4 x 512x512 bf16 = 2 MiB
  u16*   Ht    = (u16*)(ws + (size_t)( 2u << 20));  // [2][4096][512]
  u16*   Qt    = (u16*)(ws + (size_t)(10u << 20));
  u16*   Kt    = (u16*)(ws + (size_t)(18u << 20));
  u16*   Vc    = (u16*)(ws + (size_t)(26u << 20));  // [2][512][4096]
  u16*   Ot    = (u16*)(ws + (size_t)(34u << 20));
  float* stats = (float*)(ws + (size_t)(42u << 20));

  wconv_k   <<<dim3(256, 4, 1), 256, 0, stream>>>(wq, wk, wv, wo, wb);
  gn_stats_k<<<dim3(64, 1, 1),  256, 0, stream>>>(x, stats);
  gn_norm_k <<<dim3(8, 64, 2),  256, 0, stream>>>(x, gns, gnb, stats, Ht);
  gemm_nt<0><<<dim3(64, 4, 1),  256, 0, stream>>>(Ht, wb + 0u * 262144u, bq, Qt, nullptr, nullptr);
  gemm_nt<0><<<dim3(64, 4, 1),  256, 0, stream>>>(Ht, wb + 1u * 262144u, bk, Kt, nullptr, nullptr);
  gemm_nt<1><<<dim3(4, 32, 2),  256, 0, stream>>>(wb + 2u * 262144u, Ht, bv, Vc, nullptr, nullptr);
  flash_k   <<<dim3(32, 4, 2),  256, 0, stream>>>(Qt, Kt, Vc, Ot);
  gemm_nt<2><<<dim3(4, 32, 2),  256, 0, stream>>>(wb + 3u * 262144u, Ot, bo, nullptr, out, x);
}